// Round 5
// baseline (177.660 us; speedup 1.0000x reference)
//
#include <hip/hip_runtime.h>
#include <math.h>

typedef float f32x4 __attribute__((ext_vector_type(4)));
typedef short bf16x8 __attribute__((ext_vector_type(8)));
typedef unsigned short u16;

__device__ __forceinline__ u16 f2bf(float f) {
    unsigned u = __builtin_bit_cast(unsigned, f);
    u += 0x7fff + ((u >> 16) & 1);   // RNE
    return (u16)(u >> 16);
}
__device__ __forceinline__ float bf2f(u16 s) {
    unsigned v = ((unsigned)s) << 16;
    return __builtin_bit_cast(float, v);
}
__device__ __forceinline__ void gload16(const void* g, void* l) {
    __builtin_amdgcn_global_load_lds(
        (const __attribute__((address_space(1))) unsigned int*)g,
        (__attribute__((address_space(3))) unsigned int*)l, 16, 0, 0);
}

// ---------------- K0: f32 -> bf16 convert ----------------
__global__ __launch_bounds__(256) void k_f2bf(const float* __restrict__ in,
                                              u16* __restrict__ out, int n) {
    int i = (blockIdx.x * 256 + threadIdx.x) * 4;
    if (i < n) {
        float4 v = *(const float4*)(in + i);
        ushort4 o;
        o.x = f2bf(v.x); o.y = f2bf(v.y); o.z = f2bf(v.z); o.w = f2bf(v.w);
        *(ushort4*)(out + i) = o;
    }
}

// ---------------- K1: transpose + L2 normalize -> bf16 ----------------
// x [32,1024,16,8] -> xtn[b][m][c] bf16, m = t*128 + h*8 + w, row L2-normalized over c
__global__ __launch_bounds__(256) void k_transpose_norm(const float* __restrict__ x,
                                                        u16* __restrict__ xtn) {
    int b8 = blockIdx.x;   // 0..31
    int hh = blockIdx.y;   // 0..15
    int tid = threadIdx.x; // 256
    __shared__ float tile[8][1032];
    __shared__ float inv[8];
    const float* src = x + (size_t)b8 * 1024 * 128 + hh * 8;
    #pragma unroll
    for (int r = 0; r < 4; ++r) {
        int c = tid * 4 + r;
        const float* p = src + (size_t)c * 128;
        float4 v0 = *(const float4*)(p);
        float4 v1 = *(const float4*)(p + 4);
        tile[0][c] = v0.x; tile[1][c] = v0.y; tile[2][c] = v0.z; tile[3][c] = v0.w;
        tile[4][c] = v1.x; tile[5][c] = v1.y; tile[6][c] = v1.z; tile[7][c] = v1.w;
    }
    __syncthreads();
    int w = tid >> 5, j = tid & 31;
    float s = 0.f;
    #pragma unroll 8
    for (int i = 0; i < 32; ++i) { float v = tile[w][i * 32 + j]; s += v * v; }
    #pragma unroll
    for (int m = 16; m; m >>= 1) s += __shfl_xor(s, m);
    if (j == 0) inv[w] = 1.0f / fmaxf(sqrtf(s), 1e-12f);
    __syncthreads();
    int b = b8 >> 3, t = b8 & 7;
    int c0 = tid * 4;
    for (int w2 = 0; w2 < 8; ++w2) {
        int m = t * 128 + hh * 8 + w2;
        float sc = inv[w2];
        u16* dst = xtn + ((size_t)b * 1024 + m) * 1024;
        ushort4 o;
        o.x = f2bf(tile[w2][c0 + 0] * sc);
        o.y = f2bf(tile[w2][c0 + 1] * sc);
        o.z = f2bf(tile[w2][c0 + 2] * sc);
        o.w = f2bf(tile[w2][c0 + 3] * sc);
        *(ushort4*)(dst + c0) = o;
    }
}

// ---------------- K2: bf16 MFMA GEMM (BT): C[i,j] = sum_k A[i,k]*B[j,k] ----------------
// 128x128 tile, 4 waves 2x2 (64x64 each), K_STEP=32, mfma_f32_16x16x32_bf16.
// MODE 0: f32 out, no bias.  MODE 1: bf16 out + column bias.
template <int MODE>
__global__ __launch_bounds__(256) void k_mfma_gemm(
    const u16* __restrict__ A, const u16* __restrict__ B,
    float* __restrict__ Cf, u16* __restrict__ Cb,
    const float* __restrict__ bias, int K, int N,
    long long Bstr, long long Cstr)
{
    int bz = blockIdx.z;
    B += (size_t)bz * Bstr;
    int tid = threadIdx.x, lane = tid & 63, wave = tid >> 6;
    int wr = wave >> 1, wc = wave & 1;
    int i0 = blockIdx.y * 128, j0 = blockIdx.x * 128;
    __shared__ u16 As[2][128 * 32];
    __shared__ u16 Bs[2][128 * 32];
    f32x4 acc[4][4] = {};
    int lrow = lane >> 2, lk = (lane & 3) * 8;
    int fr = lane & 15, fg = lane >> 4;

    auto stage = [&](int buf, int kt) {
        #pragma unroll
        for (int q = 0; q < 2; ++q) {
            int blk = q * 4 + wave;  // 16-row block of the 128-row tile
            gload16(A + (size_t)(i0 + blk * 16 + lrow) * K + kt + lk, &As[buf][blk * 512]);
            gload16(B + (size_t)(j0 + blk * 16 + lrow) * K + kt + lk, &Bs[buf][blk * 512]);
        }
    };
    auto compute = [&](int buf) {
        bf16x8 af[4], bv[4];
        #pragma unroll
        for (int mi = 0; mi < 4; ++mi)
            af[mi] = *(const bf16x8*)&As[buf][(wr * 64 + mi * 16 + fr) * 32 + fg * 8];
        #pragma unroll
        for (int ni = 0; ni < 4; ++ni)
            bv[ni] = *(const bf16x8*)&Bs[buf][(wc * 64 + ni * 16 + fr) * 32 + fg * 8];
        #pragma unroll
        for (int mi = 0; mi < 4; ++mi)
            #pragma unroll
            for (int ni = 0; ni < 4; ++ni)
                acc[mi][ni] = __builtin_amdgcn_mfma_f32_16x16x32_bf16(
                    af[mi], bv[ni], acc[mi][ni], 0, 0, 0);
    };

    stage(0, 0);
    __syncthreads();
    int nk = K >> 5, cur = 0;
    for (int t = 0; t < nk - 1; ++t) {
        stage(cur ^ 1, (t + 1) << 5);  // prefetch next tile (in flight under MFMA)
        compute(cur);
        __syncthreads();               // vmcnt(0)+barrier: next tile ready, cur reusable
        cur ^= 1;
    }
    compute(cur);

    // epilogue: C/D layout col = lane&15, row = (lane>>4)*4 + r  [m89]
    if (MODE == 1) {
        #pragma unroll
        for (int ni = 0; ni < 4; ++ni) {
            int col = j0 + wc * 64 + ni * 16 + fr;
            float bvv = bias[col];
            #pragma unroll
            for (int mi = 0; mi < 4; ++mi)
                #pragma unroll
                for (int r = 0; r < 4; ++r) {
                    int row = i0 + wr * 64 + mi * 16 + fg * 4 + r;
                    Cb[(size_t)row * N + col] = f2bf(acc[mi][ni][r] + bvv);
                }
        }
    } else {
        float* C2 = Cf + (size_t)bz * Cstr;
        #pragma unroll
        for (int ni = 0; ni < 4; ++ni) {
            int col = j0 + wc * 64 + ni * 16 + fr;
            #pragma unroll
            for (int mi = 0; mi < 4; ++mi)
                #pragma unroll
                for (int r = 0; r < 4; ++r) {
                    int row = i0 + wr * 64 + mi * 16 + fg * 4 + r;
                    C2[(size_t)row * N + col] = acc[mi][ni][r];
                }
        }
    }
}

// ---------------- K3: alpha_g = sigmoid(h @ W_g^T + b_g), stored transposed [b][g][m] ----------------
__global__ void k_alpha_g(const u16* __restrict__ h, const float* __restrict__ Wg,
                          const float* __restrict__ bg, float* __restrict__ agT) {
    int bm = blockIdx.x;     // 0..4095
    int lane = threadIdx.x;  // 64
    const u16* hr = h + (size_t)bm * 2048;
    float acc[8] = {};
    for (int c = lane; c < 2048; c += 64) {
        float hv = bf2f(hr[c]);
        #pragma unroll
        for (int g = 0; g < 8; ++g) acc[g] += hv * Wg[g * 2048 + c];
    }
    int b = bm >> 10, m = bm & 1023;
    #pragma unroll
    for (int g = 0; g < 8; ++g) {
        float tot = acc[g];
        #pragma unroll
        for (int mm = 32; mm; mm >>= 1) tot += __shfl_xor(tot, mm);
        if (lane == g) {
            float v = tot + bg[g];
            agT[((size_t)b * 8 + g) * 1024 + m] = 1.f / (1.f + expf(-v));
        }
    }
}

// ---------------- K4: softmax over m (row of logitsT), * alpha_g, in-place; wsum ----------------
__global__ __launch_bounds__(256) void k_softmax(float* __restrict__ lt,
                                                 const float* __restrict__ agT,
                                                 float* __restrict__ wsum) {
    int gk = blockIdx.x, b = blockIdx.y;
    int tid = threadIdx.x;
    float* row = lt + ((size_t)b * 1024 + gk) * 1024;
    int g = gk >> 7;
    const float* ag = agT + ((size_t)b * 8 + g) * 1024;
    __shared__ float red[4], red2[4], red3[4];
    float4 v = *(const float4*)(row + tid * 4);
    float mx = fmaxf(fmaxf(v.x, v.y), fmaxf(v.z, v.w));
    #pragma unroll
    for (int m = 32; m; m >>= 1) mx = fmaxf(mx, __shfl_xor(mx, m));
    if ((tid & 63) == 0) red[tid >> 6] = mx;
    __syncthreads();
    mx = fmaxf(fmaxf(red[0], red[1]), fmaxf(red[2], red[3]));
    float e0 = expf(v.x - mx), e1 = expf(v.y - mx), e2 = expf(v.z - mx), e3 = expf(v.w - mx);
    float s = e0 + e1 + e2 + e3;
    #pragma unroll
    for (int m = 32; m; m >>= 1) s += __shfl_xor(s, m);
    if ((tid & 63) == 0) red2[tid >> 6] = s;
    __syncthreads();
    s = red2[0] + red2[1] + red2[2] + red2[3];
    float invs = 1.f / s;
    float4 a = *(const float4*)(ag + tid * 4);
    float w0 = e0 * invs * a.x, w1 = e1 * invs * a.y, w2 = e2 * invs * a.z, w3 = e3 * invs * a.w;
    float4 o; o.x = w0; o.y = w1; o.z = w2; o.w = w3;
    *(float4*)(row + tid * 4) = o;
    float t = w0 + w1 + w2 + w3;
    #pragma unroll
    for (int m = 32; m; m >>= 1) t += __shfl_xor(t, m);
    if ((tid & 63) == 0) red3[tid >> 6] = t;
    __syncthreads();
    if (tid == 0) wsum[((size_t)b * 8 + g) * 128 + (gk & 127)] = red3[0] + red3[1] + red3[2] + red3[3];
}

// ---------------- K4b: wf[b,g,m] = sum_k Wf[k]*w[b,gk,m];  u = Wf*wsum ----------------
__global__ __launch_bounds__(256) void k_wf_u(const float* __restrict__ wT,
                                              const float* __restrict__ wsum,
                                              const float* __restrict__ Wf,
                                              float* __restrict__ wf, float* __restrict__ u) {
    int bg = blockIdx.x;  // 0..31
    int tid = threadIdx.x;
    __shared__ float wfl[128];
    if (tid < 128) {
        wfl[tid] = Wf[tid];
        u[bg * 128 + tid] = Wf[tid] * wsum[bg * 128 + tid];
    }
    __syncthreads();
    const float* base = wT + (size_t)bg * 128 * 1024;
    float acc[4] = {};
    for (int k = 0; k < 128; ++k) {
        float wfk = wfl[k];
        const float* r = base + (size_t)k * 1024;
        #pragma unroll
        for (int q = 0; q < 4; ++q) acc[q] += wfk * r[tid + q * 256];
    }
    #pragma unroll
    for (int q = 0; q < 4; ++q) wf[(size_t)bg * 1024 + tid + q * 256] = acc[q];
}

// ---------------- K5: vf partial = sum_{m in chunk} wf[m]*h[b,m,g*256+d] ----------------
__global__ __launch_bounds__(256) void k_vf_partial(const u16* __restrict__ h,
                                                    const float* __restrict__ wf,
                                                    float* __restrict__ vfp) {
    int mc = blockIdx.x, g = blockIdx.y, b = blockIdx.z;
    int d = threadIdx.x;
    __shared__ float wl[256];
    wl[d] = wf[((size_t)b * 8 + g) * 1024 + mc * 256 + d];
    __syncthreads();
    const u16* hb = h + (size_t)b * 1024 * 2048 + (size_t)(mc * 256) * 2048 + g * 256;
    float acc = 0.f;
    #pragma unroll 8
    for (int m = 0; m < 256; ++m) acc += wl[m] * bf2f(hb[(size_t)m * 2048 + d]);
    vfp[(((size_t)(b * 8 + g)) * 4 + mc) * 256 + d] = acc;
}

// ---------------- K6: finalize vf, center, trace, S(8x8), rank-8 Newton-Schulz ----------------
#define MM8(DST, P, Q) do { if (act) { float s_ = 0.f; \
    _Pragma("unroll") \
    for (int l_ = 0; l_ < 8; ++l_) s_ += P[ii][l_] * Q[l_][jj]; \
    DST[ii][jj] = s_; } __syncthreads(); } while (0)

__global__ __launch_bounds__(256) void k_finalize(const float* __restrict__ vfp,
                                                  const float* __restrict__ u,
                                                  const float* __restrict__ cent,
                                                  const float* __restrict__ bf,
                                                  float* __restrict__ VcOut,
                                                  float* __restrict__ Wrow,
                                                  float* __restrict__ s0) {
    int b = blockIdx.x;
    int tid = threadIdx.x;  // 256
    __shared__ float ul[8][128];
    __shared__ float Vl[256][9];
    __shared__ float red[256];
    __shared__ float Sm[8][8], W1[8][8], W2[8][8], YmL[8][8], ZmL[8][8], ZYL[8][8], FmL[8][8];
    for (int i = tid; i < 1024; i += 256) ul[i >> 7][i & 127] = u[b * 1024 + i];
    __syncthreads();
    int d = tid;
    float bfv = bf[0];
    float vfl[8];
    #pragma unroll
    for (int g = 0; g < 8; ++g) {
        float acc = 0.f;
        #pragma unroll
        for (int mc = 0; mc < 4; ++mc) acc += vfp[(((size_t)(b * 8 + g)) * 4 + mc) * 256 + d];
        float ct = 0.f;
        for (int k = 0; k < 128; ++k) ct += ul[g][k] * cent[k * 256 + d];
        vfl[g] = acc - ct + bfv;
    }
    float mean = 0.f;
    #pragma unroll
    for (int g = 0; g < 8; ++g) mean += vfl[g];
    mean *= 0.125f;
    float trp = 0.f;
    #pragma unroll
    for (int g = 0; g < 8; ++g) { float v = vfl[g] - mean; Vl[d][g] = v; trp += v * v; }
    red[tid] = trp;
    __syncthreads();
    for (int s = 128; s > 0; s >>= 1) { if (tid < s) red[tid] += red[tid + s]; __syncthreads(); }
    float tr = red[0] * 0.125f;  // trace(cov)
    bool act = tid < 64;
    int ii = (tid >> 3) & 7, jj = tid & 7;
    if (act) {
        float sv = 0.f;
        for (int dd = 0; dd < 256; ++dd) sv += Vl[dd][ii] * Vl[dd][jj];
        Sm[ii][jj] = sv / (8.f * tr);
    }
    __syncthreads();
    // representation: mat = a*I + U B U^T, S = U^T U; product (a,P)(c,Q)=(ac, aQ+cP+P S Q)
    if (act) {
        YmL[ii][jj] = (ii == jj ? 1.5f : 0.f) - 0.5f * Sm[ii][jj];
        ZmL[ii][jj] = (ii == jj ? -0.5f : 0.f);
    }
    __syncthreads();
    float ya = 0.f, za = 1.5f;
    MM8(W1, Sm, YmL);
    MM8(W2, ZmL, W1);
    float pa = za * ya;
    if (act) ZYL[ii][jj] = -0.5f * (za * YmL[ii][jj] + ya * ZmL[ii][jj] + W2[ii][jj]);
    __syncthreads();
    float zya = 1.5f - 0.5f * pa;
    MM8(W1, Sm, ZYL);
    MM8(W2, YmL, W1);
    if (act) YmL[ii][jj] = ya * ZYL[ii][jj] + zya * YmL[ii][jj] + W2[ii][jj];
    __syncthreads();
    ya = ya * zya;
    MM8(W1, Sm, ZmL);
    MM8(W2, ZYL, W1);
    if (act) ZmL[ii][jj] = zya * ZmL[ii][jj] + za * ZYL[ii][jj] + W2[ii][jj];
    __syncthreads();
    za = zya * za;
    MM8(W1, Sm, YmL);
    MM8(W2, ZmL, W1);
    float p2a = za * ya;
    if (act) ZYL[ii][jj] = za * YmL[ii][jj] + ya * ZmL[ii][jj] + W2[ii][jj];
    __syncthreads();
    MM8(W1, Sm, ZYL);
    MM8(W2, YmL, W1);
    if (act) FmL[ii][jj] = 0.5f * ((3.f - p2a) * YmL[ii][jj] - ya * ZYL[ii][jj] - W2[ii][jj]);
    __syncthreads();
    float fa = 0.5f * ya * (3.f - p2a);
    float sqtr = sqrtf(tr);
    float scaleF = 1.f / (8.f * sqtr);
    #pragma unroll
    for (int jo = 0; jo < 8; ++jo) {
        float sv = 0.f;
        #pragma unroll
        for (int i = 0; i < 8; ++i) sv += Vl[d][i] * FmL[i][jo];
        Wrow[((size_t)b * 256 + d) * 8 + jo] = sv * scaleF;
    }
    #pragma unroll
    for (int jo = 0; jo < 8; ++jo) VcOut[((size_t)b * 256 + d) * 8 + jo] = Vl[d][jo];
    if (tid == 0) s0[b] = fa * sqtr;
}

// ---------------- K7: triuvec output: R[d,e] = s0*delta + Wrow[d,:].Vc[e,:] ----------------
__global__ __launch_bounds__(256) void k_output(const float* __restrict__ Vc,
                                                const float* __restrict__ Wrow,
                                                const float* __restrict__ s0,
                                                float* __restrict__ out) {
    int dd = blockIdx.x, b = blockIdx.y;
    int e = threadIdx.x;
    __shared__ float Vl[256][9];
    __shared__ float wr[8];
    float4 v0 = *(const float4*)(Vc + ((size_t)b * 256 + e) * 8);
    float4 v1 = *(const float4*)(Vc + ((size_t)b * 256 + e) * 8 + 4);
    Vl[e][0] = v0.x; Vl[e][1] = v0.y; Vl[e][2] = v0.z; Vl[e][3] = v0.w;
    Vl[e][4] = v1.x; Vl[e][5] = v1.y; Vl[e][6] = v1.z; Vl[e][7] = v1.w;
    if (e < 8) wr[e] = Wrow[((size_t)b * 256 + dd) * 8 + e];
    __syncthreads();
    if (e >= dd) {
        float v = (e == dd) ? s0[b] : 0.f;
        #pragma unroll
        for (int j = 0; j < 8; ++j) v += wr[j] * Vl[e][j];
        size_t idx = (size_t)b * 32896 + (size_t)dd * 256 - ((size_t)dd * (dd - 1)) / 2 + (e - dd);
        out[idx] = v;
    }
}

extern "C" void kernel_launch(void* const* d_in, const int* in_sizes, int n_in,
                              void* d_out, int out_size, void* d_ws, size_t ws_size,
                              hipStream_t stream) {
    const float* x    = (const float*)d_in[0];
    const float* cent = (const float*)d_in[1];
    const float* Winp = (const float*)d_in[2];
    const float* binp = (const float*)d_in[3];
    const float* Wg   = (const float*)d_in[4];
    const float* bg   = (const float*)d_in[5];
    const float* Wgk  = (const float*)d_in[6];
    const float* Wf   = (const float*)d_in[8];
    const float* bf   = (const float*)d_in[9];
    float* out = (float*)d_out;
    char* wsb = (char*)d_ws;

    // byte-offset workspace layout
    float* lt    = (float*)(wsb);                        // [4][1024][1024] f32, 16 MB
    u16*   xtnb  = (u16*)(wsb);                          // alias (dead before lt written), 8 MB
    u16*   hb    = (u16*)(wsb + (16ull << 20));          // [4096][2048] bf16, 16 MB
    u16*   winpb = (u16*)(wsb + (32ull << 20));          // [2048][1024] bf16, 4 MB
    u16*   wgkb  = (u16*)(wsb + (36ull << 20));          // [1024][2048] bf16, 4 MB
    float* agT   = (float*)(wsb + (40ull << 20));
    float* wsum  = agT + 32768;
    float* wf    = wsum + 4096;
    float* u     = wf + 32768;
    float* vfp   = u + 4096;
    float* Vc    = vfp + 32768;
    float* Wr    = Vc + 8192;
    float* s0    = Wr + 8192;

    k_transpose_norm<<<dim3(32, 16), 256, 0, stream>>>(x, xtnb);
    k_f2bf<<<2048, 256, 0, stream>>>(Winp, winpb, 2097152);
    k_f2bf<<<2048, 256, 0, stream>>>(Wgk, wgkb, 2097152);
    // GEMM1: h[bm,j] = xtn @ W_inp^T + b_inp -> bf16  (M=4096, N=2048, K=1024)
    k_mfma_gemm<1><<<dim3(16, 32, 1), 256, 0, stream>>>(
        xtnb, winpb, nullptr, hb, binp, 1024, 2048, 0, 0);
    k_alpha_g<<<4096, 64, 0, stream>>>(hb, Wg, bg, agT);
    // GEMM2: logitsT[b][gk][m] = W_gk @ h_b^T -> f32  (M=1024, N=1024, K=2048, z=4)
    // (bias omitted: softmax over m is shift-invariant)
    k_mfma_gemm<0><<<dim3(8, 8, 4), 256, 0, stream>>>(
        wgkb, hb, lt, nullptr, nullptr, 2048, 1024, 2097152LL, 1048576LL);
    k_softmax<<<dim3(1024, 4), 256, 0, stream>>>(lt, agT, wsum);
    k_wf_u<<<32, 256, 0, stream>>>(lt, wsum, Wf, wf, u);
    k_vf_partial<<<dim3(4, 8, 4), 256, 0, stream>>>(hb, wf, vfp);
    k_finalize<<<4, 256, 0, stream>>>(vfp, u, cent, bf, Vc, Wr, s0);
    k_output<<<dim3(256, 4), 256, 0, stream>>>(Vc, Wr, s0, out);
}

// Round 6
// 131.519 us; speedup vs baseline: 1.3508x; 1.3508x over previous
//
#include <hip/hip_runtime.h>
#include <math.h>

typedef float f32x4 __attribute__((ext_vector_type(4)));
typedef short bf16x8 __attribute__((ext_vector_type(8)));
typedef unsigned short u16;

__device__ __forceinline__ u16 f2bf(float f) {
    unsigned u = __builtin_bit_cast(unsigned, f);
    u += 0x7fff + ((u >> 16) & 1);   // RNE
    return (u16)(u >> 16);
}
__device__ __forceinline__ float bf2f(u16 s) {
    unsigned v = ((unsigned)s) << 16;
    return __builtin_bit_cast(float, v);
}
__device__ __forceinline__ void gload16(const void* g, void* l) {
    __builtin_amdgcn_global_load_lds(
        (const __attribute__((address_space(1))) unsigned int*)g,
        (__attribute__((address_space(3))) unsigned int*)l, 16, 0, 0);
}

// ---------------- K0: f32 -> bf16 convert (two sources, adjacent dests) ----------------
__global__ __launch_bounds__(256) void k_f2bf2(const float* __restrict__ a,
                                               const float* __restrict__ b,
                                               u16* __restrict__ out, int na, int n) {
    int i = (blockIdx.x * 256 + threadIdx.x) * 4;
    if (i < n) {
        const float* src = (i < na) ? (a + i) : (b + (i - na));
        float4 v = *(const float4*)src;
        ushort4 o;
        o.x = f2bf(v.x); o.y = f2bf(v.y); o.z = f2bf(v.z); o.w = f2bf(v.w);
        *(ushort4*)(out + i) = o;
    }
}

// ---------------- K1: transpose + L2 normalize -> bf16 ----------------
// x [32,1024,16,8] -> xtn[b][m][c] bf16, m = t*128 + h*8 + w, row L2-normalized over c
__global__ __launch_bounds__(256) void k_transpose_norm(const float* __restrict__ x,
                                                        u16* __restrict__ xtn) {
    int b8 = blockIdx.x;   // 0..31
    int hh = blockIdx.y;   // 0..15
    int tid = threadIdx.x; // 256
    __shared__ float tile[8][1032];
    __shared__ float inv[8];
    const float* src = x + (size_t)b8 * 1024 * 128 + hh * 8;
    #pragma unroll
    for (int r = 0; r < 4; ++r) {
        int c = tid * 4 + r;
        const float* p = src + (size_t)c * 128;
        float4 v0 = *(const float4*)(p);
        float4 v1 = *(const float4*)(p + 4);
        tile[0][c] = v0.x; tile[1][c] = v0.y; tile[2][c] = v0.z; tile[3][c] = v0.w;
        tile[4][c] = v1.x; tile[5][c] = v1.y; tile[6][c] = v1.z; tile[7][c] = v1.w;
    }
    __syncthreads();
    int w = tid >> 5, j = tid & 31;
    float s = 0.f;
    #pragma unroll 8
    for (int i = 0; i < 32; ++i) { float v = tile[w][i * 32 + j]; s += v * v; }
    #pragma unroll
    for (int m = 16; m; m >>= 1) s += __shfl_xor(s, m);
    if (j == 0) inv[w] = 1.0f / fmaxf(sqrtf(s), 1e-12f);
    __syncthreads();
    int b = b8 >> 3, t = b8 & 7;
    int c0 = tid * 4;
    for (int w2 = 0; w2 < 8; ++w2) {
        int m = t * 128 + hh * 8 + w2;
        float sc = inv[w2];
        u16* dst = xtn + ((size_t)b * 1024 + m) * 1024;
        ushort4 o;
        o.x = f2bf(tile[w2][c0 + 0] * sc);
        o.y = f2bf(tile[w2][c0 + 1] * sc);
        o.z = f2bf(tile[w2][c0 + 2] * sc);
        o.w = f2bf(tile[w2][c0 + 3] * sc);
        *(ushort4*)(dst + c0) = o;
    }
}

// ---------------- K2: bf16 MFMA GEMM (BT): C[i,j] = sum_k A[i,k]*B[j,k] ----------------
// 128x128 tile, 4 waves 2x2 (64x64 each), K_STEP=32, mfma_f32_16x16x32_bf16.
// Ring-3 LDS buffers + counted vmcnt (T4): wait only on loads issued 2 iters ago,
// raw s_barrier (no vmcnt(0) drain of the fresh prefetch).
// LDS chunk-XOR swizzle (both-sides, rule #21): global source chunk pre-permuted,
// ds_read chunk XOR'd with the same key -> 8-way bank conflict becomes 2-way (free).
// MODE 0: f32 out, no bias.  MODE 1: bf16 out + column bias.
template <int MODE>
__global__ __launch_bounds__(256) void k_mfma_gemm(
    const u16* __restrict__ A, const u16* __restrict__ B,
    float* __restrict__ Cf, u16* __restrict__ Cb,
    const float* __restrict__ bias, int K, int N,
    long long Bstr, long long Cstr)
{
    int bz = blockIdx.z;
    B += (size_t)bz * Bstr;
    int tid = threadIdx.x, lane = tid & 63, wave = tid >> 6;
    int wr = wave >> 1, wc = wave & 1;
    int i0 = blockIdx.y * 128, j0 = blockIdx.x * 128;
    __shared__ u16 As[3][128 * 32];
    __shared__ u16 Bs[3][128 * 32];
    f32x4 acc[4][4] = {};
    int lrow = lane >> 2;
    // staged: LDS[row][cl] = G[row][cl ^ s(row)], s(row) = (row>>1)&3 (row mod 16 pattern)
    int lk = ((lane & 3) ^ ((lane >> 3) & 3)) * 8;   // global chunk for this lane (pre-swizzle)
    int fr = lane & 15, fg = lane >> 4;
    int ca = (fg ^ ((fr >> 1) & 3)) * 8;             // read-side chunk XOR (same involution)

    auto stage = [&](int buf, int t) {
        int kt = t << 5;
        #pragma unroll
        for (int q = 0; q < 2; ++q) {
            int blk = q * 4 + wave;  // 16-row block of the 128-row tile
            gload16(A + (size_t)(i0 + blk * 16 + lrow) * K + kt + lk, &As[buf][blk * 512]);
            gload16(B + (size_t)(j0 + blk * 16 + lrow) * K + kt + lk, &Bs[buf][blk * 512]);
        }
    };
    auto compute = [&](int buf) {
        bf16x8 af[4], bv[4];
        #pragma unroll
        for (int mi = 0; mi < 4; ++mi)
            af[mi] = *(const bf16x8*)&As[buf][(wr * 64 + mi * 16 + fr) * 32 + ca];
        #pragma unroll
        for (int ni = 0; ni < 4; ++ni)
            bv[ni] = *(const bf16x8*)&Bs[buf][(wc * 64 + ni * 16 + fr) * 32 + ca];
        #pragma unroll
        for (int mi = 0; mi < 4; ++mi)
            #pragma unroll
            for (int ni = 0; ni < 4; ++ni)
                acc[mi][ni] = __builtin_amdgcn_mfma_f32_16x16x32_bf16(
                    af[mi], bv[ni], acc[mi][ni], 0, 0, 0);
    };

    int nk = K >> 5;
    stage(0, 0);
    stage(1, 1);
    int cur = 0;
    for (int t = 0; t < nk; ++t) {
        if (t + 2 < nk) {
            int nb = cur + 2; if (nb >= 3) nb -= 3;
            stage(nb, t + 2);                              // 4 loads/wave into just-freed buf
            asm volatile("s_waitcnt vmcnt(8)" ::: "memory");   // own loads for buf cur done
        } else if (t + 1 < nk) {
            asm volatile("s_waitcnt vmcnt(4)" ::: "memory");
        } else {
            asm volatile("s_waitcnt vmcnt(0)" ::: "memory");
        }
        __builtin_amdgcn_s_barrier();    // all waves' loads for buf cur done
        compute(cur);
        __builtin_amdgcn_s_barrier();    // all waves done reading buf cur -> reusable
        ++cur; if (cur == 3) cur = 0;
    }

    // epilogue: C/D layout col = lane&15, row = (lane>>4)*4 + r  [m89]
    if (MODE == 1) {
        #pragma unroll
        for (int ni = 0; ni < 4; ++ni) {
            int col = j0 + wc * 64 + ni * 16 + fr;
            float bvv = bias[col];
            #pragma unroll
            for (int mi = 0; mi < 4; ++mi)
                #pragma unroll
                for (int r = 0; r < 4; ++r) {
                    int row = i0 + wr * 64 + mi * 16 + fg * 4 + r;
                    Cb[(size_t)row * N + col] = f2bf(acc[mi][ni][r] + bvv);
                }
        }
    } else {
        float* C2 = Cf + (size_t)bz * Cstr;
        #pragma unroll
        for (int ni = 0; ni < 4; ++ni) {
            int col = j0 + wc * 64 + ni * 16 + fr;
            #pragma unroll
            for (int mi = 0; mi < 4; ++mi)
                #pragma unroll
                for (int r = 0; r < 4; ++r) {
                    int row = i0 + wr * 64 + mi * 16 + fg * 4 + r;
                    C2[(size_t)row * N + col] = acc[mi][ni][r];
                }
        }
    }
}

// ---------------- K3: alpha_g = sigmoid(h @ W_g^T + b_g), stored transposed [b][g][m] ----------------
// m-batched: 16 rows/block, Wg staged once in LDS (L2 Wg traffic 256MB -> 16MB)
__global__ __launch_bounds__(256) void k_alpha_g(const u16* __restrict__ h,
                                                 const float* __restrict__ Wg,
                                                 const float* __restrict__ bg,
                                                 float* __restrict__ agT) {
    __shared__ float wgl[16384];  // Wg [8][2048] f32 = 64KB
    int tid = threadIdx.x;
    #pragma unroll
    for (int i = 0; i < 16; ++i) {
        int idx = tid * 4 + i * 1024;
        *(float4*)&wgl[idx] = *(const float4*)&Wg[idx];
    }
    __syncthreads();
    float bgl[8];
    #pragma unroll
    for (int g = 0; g < 8; ++g) bgl[g] = bg[g];
    int wv = tid >> 6, lane = tid & 63;
    int bm0 = blockIdx.x * 16;
    for (int r = 0; r < 4; ++r) {
        int bm = bm0 + wv * 4 + r;
        const u16* hr = h + (size_t)bm * 2048;
        float acc[8] = {};
        #pragma unroll
        for (int i = 0; i < 4; ++i) {
            int c0 = i * 512 + lane * 8;
            bf16x8 hv8 = *(const bf16x8*)(hr + c0);
            float hf[8];
            #pragma unroll
            for (int j = 0; j < 8; ++j) hf[j] = bf2f((u16)hv8[j]);
            #pragma unroll
            for (int g = 0; g < 8; ++g) {
                const float* wrp = &wgl[g * 2048 + c0];
                #pragma unroll
                for (int j = 0; j < 8; ++j) acc[g] += hf[j] * wrp[j];
            }
        }
        #pragma unroll
        for (int g = 0; g < 8; ++g) {
            #pragma unroll
            for (int off = 32; off; off >>= 1) acc[g] += __shfl_xor(acc[g], off);
        }
        if (lane < 8) {
            int b = bm >> 10, m = bm & 1023;
            agT[((size_t)b * 8 + lane) * 1024 + m] =
                1.f / (1.f + expf(-(acc[lane] + bgl[lane])));
        }
    }
}

// ---------------- K4: softmax over m (row of logitsT), * alpha_g, in-place; wsum ----------------
__global__ __launch_bounds__(256) void k_softmax(float* __restrict__ lt,
                                                 const float* __restrict__ agT,
                                                 float* __restrict__ wsum) {
    int gk = blockIdx.x, b = blockIdx.y;
    int tid = threadIdx.x;
    float* row = lt + ((size_t)b * 1024 + gk) * 1024;
    int g = gk >> 7;
    const float* ag = agT + ((size_t)b * 8 + g) * 1024;
    __shared__ float red[4], red2[4], red3[4];
    float4 v = *(const float4*)(row + tid * 4);
    float mx = fmaxf(fmaxf(v.x, v.y), fmaxf(v.z, v.w));
    #pragma unroll
    for (int m = 32; m; m >>= 1) mx = fmaxf(mx, __shfl_xor(mx, m));
    if ((tid & 63) == 0) red[tid >> 6] = mx;
    __syncthreads();
    mx = fmaxf(fmaxf(red[0], red[1]), fmaxf(red[2], red[3]));
    float e0 = expf(v.x - mx), e1 = expf(v.y - mx), e2 = expf(v.z - mx), e3 = expf(v.w - mx);
    float s = e0 + e1 + e2 + e3;
    #pragma unroll
    for (int m = 32; m; m >>= 1) s += __shfl_xor(s, m);
    if ((tid & 63) == 0) red2[tid >> 6] = s;
    __syncthreads();
    s = red2[0] + red2[1] + red2[2] + red2[3];
    float invs = 1.f / s;
    float4 a = *(const float4*)(ag + tid * 4);
    float w0 = e0 * invs * a.x, w1 = e1 * invs * a.y, w2 = e2 * invs * a.z, w3 = e3 * invs * a.w;
    float4 o; o.x = w0; o.y = w1; o.z = w2; o.w = w3;
    *(float4*)(row + tid * 4) = o;
    float t = w0 + w1 + w2 + w3;
    #pragma unroll
    for (int m = 32; m; m >>= 1) t += __shfl_xor(t, m);
    if ((tid & 63) == 0) red3[tid >> 6] = t;
    __syncthreads();
    if (tid == 0) wsum[((size_t)b * 8 + g) * 128 + (gk & 127)] = red3[0] + red3[1] + red3[2] + red3[3];
}

// ---------------- K4b: wf[b,g,m] = sum_k Wf[k]*w[b,gk,m];  u = Wf*wsum ----------------
// grid (8 m-segs, 32 bg): 256 blocks (was 32), k split 2x128 threads
__global__ __launch_bounds__(256) void k_wf_u(const float* __restrict__ wT,
                                              const float* __restrict__ wsum,
                                              const float* __restrict__ Wf,
                                              float* __restrict__ wf, float* __restrict__ u) {
    int ms = blockIdx.x, bg = blockIdx.y;
    int tid = threadIdx.x;
    __shared__ float wfl[128];
    __shared__ float part[256];
    if (tid < 128) {
        wfl[tid] = Wf[tid];
        if (ms == 0) u[bg * 128 + tid] = Wf[tid] * wsum[bg * 128 + tid];
    }
    __syncthreads();
    int ml = tid & 127;
    int kh = tid >> 7;
    const float* base = wT + (size_t)bg * 131072 + (size_t)kh * 64 * 1024 + ms * 128;
    float acc = 0.f;
    #pragma unroll 4
    for (int k = 0; k < 64; ++k) acc += wfl[kh * 64 + k] * base[(size_t)k * 1024 + ml];
    part[tid] = acc;
    __syncthreads();
    if (tid < 128) wf[(size_t)bg * 1024 + ms * 128 + ml] = part[tid] + part[tid + 128];
}

// ---------------- K5: vf partials: mc<16 -> sum_{m chunk} wf[m]*h; mc==16 -> -centroid term ----------------
__global__ __launch_bounds__(256) void k_vf_partial(const u16* __restrict__ h,
                                                    const float* __restrict__ wf,
                                                    const float* __restrict__ u,
                                                    const float* __restrict__ cent,
                                                    float* __restrict__ vfp) {
    int mc = blockIdx.x;  // 0..16
    int g = blockIdx.y, b = blockIdx.z;
    int d = threadIdx.x;
    __shared__ float wl[64];
    __shared__ float ul[128];
    float acc = 0.f;
    if (mc < 16) {
        if (d < 64) wl[d] = wf[((size_t)b * 8 + g) * 1024 + mc * 64 + d];
        __syncthreads();
        const u16* hb = h + (size_t)b * 1024 * 2048 + (size_t)(mc * 64) * 2048 + g * 256;
        #pragma unroll 4
        for (int m = 0; m < 64; ++m) acc += wl[m] * bf2f(hb[(size_t)m * 2048 + d]);
    } else {
        if (d < 128) ul[d] = u[((size_t)b * 8 + g) * 128 + d];
        __syncthreads();
        for (int k = 0; k < 128; ++k) acc -= ul[k] * cent[k * 256 + d];
    }
    vfp[(((size_t)b * 8 + g) * 17 + mc) * 256 + d] = acc;
}

// ---------------- K6: finalize vf, center, trace, S(8x8), rank-8 Newton-Schulz ----------------
#define MM8(DST, P, Q) do { if (act) { float s_ = 0.f; \
    _Pragma("unroll") \
    for (int l_ = 0; l_ < 8; ++l_) s_ += P[ii][l_] * Q[l_][jj]; \
    DST[ii][jj] = s_; } __syncthreads(); } while (0)

__global__ __launch_bounds__(256) void k_finalize(const float* __restrict__ vfp,
                                                  const float* __restrict__ bf,
                                                  float* __restrict__ VcOut,
                                                  float* __restrict__ Wrow,
                                                  float* __restrict__ s0) {
    int b = blockIdx.x;
    int tid = threadIdx.x;  // 256
    __shared__ float Vl[256][9];
    __shared__ float red[256];
    __shared__ float Sm[8][8], W1[8][8], W2[8][8], YmL[8][8], ZmL[8][8], ZYL[8][8], FmL[8][8];
    int d = tid;
    float bfv = bf[0];
    float vfl[8];
    #pragma unroll
    for (int g = 0; g < 8; ++g) {
        float acc = 0.f;
        for (int mc = 0; mc < 17; ++mc)
            acc += vfp[(((size_t)b * 8 + g) * 17 + mc) * 256 + d];
        vfl[g] = acc + bfv;
    }
    float mean = 0.f;
    #pragma unroll
    for (int g = 0; g < 8; ++g) mean += vfl[g];
    mean *= 0.125f;
    float trp = 0.f;
    #pragma unroll
    for (int g = 0; g < 8; ++g) { float v = vfl[g] - mean; Vl[d][g] = v; trp += v * v; }
    red[tid] = trp;
    __syncthreads();
    for (int s = 128; s > 0; s >>= 1) { if (tid < s) red[tid] += red[tid + s]; __syncthreads(); }
    float tr = red[0] * 0.125f;  // trace(cov)
    bool act = tid < 64;
    int ii = (tid >> 3) & 7, jj = tid & 7;
    if (act) {
        float sv = 0.f;
        for (int dd = 0; dd < 256; ++dd) sv += Vl[dd][ii] * Vl[dd][jj];
        Sm[ii][jj] = sv / (8.f * tr);
    }
    __syncthreads();
    // representation: mat = a*I + U B U^T, S = U^T U; product (a,P)(c,Q)=(ac, aQ+cP+P S Q)
    if (act) {
        YmL[ii][jj] = (ii == jj ? 1.5f : 0.f) - 0.5f * Sm[ii][jj];
        ZmL[ii][jj] = (ii == jj ? -0.5f : 0.f);
    }
    __syncthreads();
    float ya = 0.f, za = 1.5f;
    MM8(W1, Sm, YmL);
    MM8(W2, ZmL, W1);
    float pa = za * ya;
    if (act) ZYL[ii][jj] = -0.5f * (za * YmL[ii][jj] + ya * ZmL[ii][jj] + W2[ii][jj]);
    __syncthreads();
    float zya = 1.5f - 0.5f * pa;
    MM8(W1, Sm, ZYL);
    MM8(W2, YmL, W1);
    if (act) YmL[ii][jj] = ya * ZYL[ii][jj] + zya * YmL[ii][jj] + W2[ii][jj];
    __syncthreads();
    ya = ya * zya;
    MM8(W1, Sm, ZmL);
    MM8(W2, ZYL, W1);
    if (act) ZmL[ii][jj] = zya * ZmL[ii][jj] + za * ZYL[ii][jj] + W2[ii][jj];
    __syncthreads();
    za = zya * za;
    MM8(W1, Sm, YmL);
    MM8(W2, ZmL, W1);
    float p2a = za * ya;
    if (act) ZYL[ii][jj] = za * YmL[ii][jj] + ya * ZmL[ii][jj] + W2[ii][jj];
    __syncthreads();
    MM8(W1, Sm, ZYL);
    MM8(W2, YmL, W1);
    if (act) FmL[ii][jj] = 0.5f * ((3.f - p2a) * YmL[ii][jj] - ya * ZYL[ii][jj] - W2[ii][jj]);
    __syncthreads();
    float fa = 0.5f * ya * (3.f - p2a);
    float sqtr = sqrtf(tr);
    float scaleF = 1.f / (8.f * sqtr);
    #pragma unroll
    for (int jo = 0; jo < 8; ++jo) {
        float sv = 0.f;
        #pragma unroll
        for (int i = 0; i < 8; ++i) sv += Vl[d][i] * FmL[i][jo];
        Wrow[((size_t)b * 256 + d) * 8 + jo] = sv * scaleF;
    }
    #pragma unroll
    for (int jo = 0; jo < 8; ++jo) VcOut[((size_t)b * 256 + d) * 8 + jo] = Vl[d][jo];
    if (tid == 0) s0[b] = fa * sqtr;
}

// ---------------- K7: triuvec output: R[d,e] = s0*delta + Wrow[d,:].Vc[e,:] ----------------
__global__ __launch_bounds__(256) void k_output(const float* __restrict__ Vc,
                                                const float* __restrict__ Wrow,
                                                const float* __restrict__ s0,
                                                float* __restrict__ out) {
    int dd = blockIdx.x, b = blockIdx.y;
    int e = threadIdx.x;
    __shared__ float Vl[256][9];
    __shared__ float wr[8];
    float4 v0 = *(const float4*)(Vc + ((size_t)b * 256 + e) * 8);
    float4 v1 = *(const float4*)(Vc + ((size_t)b * 256 + e) * 8 + 4);
    Vl[e][0] = v0.x; Vl[e][1] = v0.y; Vl[e][2] = v0.z; Vl[e][3] = v0.w;
    Vl[e][4] = v1.x; Vl[e][5] = v1.y; Vl[e][6] = v1.z; Vl[e][7] = v1.w;
    if (e < 8) wr[e] = Wrow[((size_t)b * 256 + dd) * 8 + e];
    __syncthreads();
    if (e >= dd) {
        float v = (e == dd) ? s0[b] : 0.f;
        #pragma unroll
        for (int j = 0; j < 8; ++j) v += wr[j] * Vl[e][j];
        size_t idx = (size_t)b * 32896 + (size_t)dd * 256 - ((size_t)dd * (dd - 1)) / 2 + (e - dd);
        out[idx] = v;
    }
}

extern "C" void kernel_launch(void* const* d_in, const int* in_sizes, int n_in,
                              void* d_out, int out_size, void* d_ws, size_t ws_size,
                              hipStream_t stream) {
    const float* x    = (const float*)d_in[0];
    const float* cent = (const float*)d_in[1];
    const float* Winp = (const float*)d_in[2];
    const float* binp = (const float*)d_in[3];
    const float* Wg   = (const float*)d_in[4];
    const float* bg   = (const float*)d_in[5];
    const float* Wgk  = (const float*)d_in[6];
    const float* Wf   = (const float*)d_in[8];
    const float* bf   = (const float*)d_in[9];
    float* out = (float*)d_out;
    char* wsb = (char*)d_ws;

    // byte-offset workspace layout
    float* lt    = (float*)(wsb);                        // [4][1024][1024] f32, 16 MB
    u16*   xtnb  = (u16*)(wsb);                          // alias (dead before lt written), 8 MB
    u16*   hb    = (u16*)(wsb + (16ull << 20));          // [4096][2048] bf16, 16 MB
    u16*   winpb = (u16*)(wsb + (32ull << 20));          // [2048][1024] bf16, 4 MB
    u16*   wgkb  = (u16*)(wsb + (36ull << 20));          // [1024][2048] bf16, 4 MB (adjacent to winpb)
    float* agT   = (float*)(wsb + (40ull << 20));
    float* wsum  = agT + 32768;
    float* wf    = wsum + 4096;
    float* u     = wf + 32768;
    float* vfp   = u + 4096;                             // [4][8][17][256]
    float* Vc    = vfp + 139264;
    float* Wr    = Vc + 8192;
    float* s0    = Wr + 8192;

    k_transpose_norm<<<dim3(32, 16), 256, 0, stream>>>(x, xtnb);
    k_f2bf2<<<4096, 256, 0, stream>>>(Winp, Wgk, winpb, 2097152, 4194304);
    // GEMM1: h[bm,j] = xtn @ W_inp^T + b_inp -> bf16  (M=4096, N=2048, K=1024)
    k_mfma_gemm<1><<<dim3(16, 32, 1), 256, 0, stream>>>(
        xtnb, winpb, nullptr, hb, binp, 1024, 2048, 0, 0);
    k_alpha_g<<<256, 256, 0, stream>>>(hb, Wg, bg, agT);
    // GEMM2: logitsT[b][gk][m] = W_gk @ h_b^T -> f32  (M=1024, N=1024, K=2048, z=4)
    // (bias omitted: softmax over m is shift-invariant)
    k_mfma_gemm<0><<<dim3(8, 8, 4), 256, 0, stream>>>(
        wgkb, hb, lt, nullptr, nullptr, 2048, 1024, 2097152LL, 1048576LL);
    k_softmax<<<dim3(1024, 4), 256, 0, stream>>>(lt, agT, wsum);
    k_wf_u<<<dim3(8, 32), 256, 0, stream>>>(lt, wsum, Wf, wf, u);
    k_vf_partial<<<dim3(17, 8, 4), 256, 0, stream>>>(hb, wf, u, cent, vfp);
    k_finalize<<<4, 256, 0, stream>>>(vfp, bf, Vc, Wr, s0);
    k_output<<<dim3(256, 4), 256, 0, stream>>>(Vc, Wr, s0, out);
}

// Round 7
// 123.889 us; speedup vs baseline: 1.4340x; 1.0616x over previous
//
#include <hip/hip_runtime.h>
#include <math.h>

typedef float f32x4 __attribute__((ext_vector_type(4)));
typedef short bf16x8 __attribute__((ext_vector_type(8)));
typedef unsigned short u16;

__device__ __forceinline__ u16 f2bf(float f) {
    unsigned u = __builtin_bit_cast(unsigned, f);
    u += 0x7fff + ((u >> 16) & 1);   // RNE
    return (u16)(u >> 16);
}
__device__ __forceinline__ float bf2f(u16 s) {
    unsigned v = ((unsigned)s) << 16;
    return __builtin_bit_cast(float, v);
}
__device__ __forceinline__ void gload16(const void* g, void* l) {
    __builtin_amdgcn_global_load_lds(
        (const __attribute__((address_space(1))) unsigned int*)g,
        (__attribute__((address_space(3))) unsigned int*)l, 16, 0, 0);
}

// ---------------- K0: f32 -> bf16 convert (two sources, adjacent dests) ----------------
__global__ __launch_bounds__(256) void k_f2bf2(const float* __restrict__ a,
                                               const float* __restrict__ b,
                                               u16* __restrict__ out, int na, int n) {
    int i = (blockIdx.x * 256 + threadIdx.x) * 4;
    if (i < n) {
        const float* src = (i < na) ? (a + i) : (b + (i - na));
        float4 v = *(const float4*)src;
        ushort4 o;
        o.x = f2bf(v.x); o.y = f2bf(v.y); o.z = f2bf(v.z); o.w = f2bf(v.w);
        *(ushort4*)(out + i) = o;
    }
}

// ---------------- K1: transpose + L2 normalize -> bf16 ----------------
__global__ __launch_bounds__(256) void k_transpose_norm(const float* __restrict__ x,
                                                        u16* __restrict__ xtn) {
    int b8 = blockIdx.x;   // 0..31
    int hh = blockIdx.y;   // 0..15
    int tid = threadIdx.x; // 256
    __shared__ float tile[8][1032];
    __shared__ float inv[8];
    const float* src = x + (size_t)b8 * 1024 * 128 + hh * 8;
    #pragma unroll
    for (int r = 0; r < 4; ++r) {
        int c = tid * 4 + r;
        const float* p = src + (size_t)c * 128;
        float4 v0 = *(const float4*)(p);
        float4 v1 = *(const float4*)(p + 4);
        tile[0][c] = v0.x; tile[1][c] = v0.y; tile[2][c] = v0.z; tile[3][c] = v0.w;
        tile[4][c] = v1.x; tile[5][c] = v1.y; tile[6][c] = v1.z; tile[7][c] = v1.w;
    }
    __syncthreads();
    int w = tid >> 5, j = tid & 31;
    float s = 0.f;
    #pragma unroll 8
    for (int i = 0; i < 32; ++i) { float v = tile[w][i * 32 + j]; s += v * v; }
    #pragma unroll
    for (int m = 16; m; m >>= 1) s += __shfl_xor(s, m);
    if (j == 0) inv[w] = 1.0f / fmaxf(sqrtf(s), 1e-12f);
    __syncthreads();
    int b = b8 >> 3, t = b8 & 7;
    int c0 = tid * 4;
    for (int w2 = 0; w2 < 8; ++w2) {
        int m = t * 128 + hh * 8 + w2;
        float sc = inv[w2];
        u16* dst = xtn + ((size_t)b * 1024 + m) * 1024;
        ushort4 o;
        o.x = f2bf(tile[w2][c0 + 0] * sc);
        o.y = f2bf(tile[w2][c0 + 1] * sc);
        o.z = f2bf(tile[w2][c0 + 2] * sc);
        o.w = f2bf(tile[w2][c0 + 3] * sc);
        *(ushort4*)(dst + c0) = o;
    }
}

// ---------------- K2: bf16 MFMA GEMM (BT): C[i,j] = sum_k A[i,k]*B[j,k] ----------------
// BK=64, 8 waves (512 thr), wave-tile (BM/WR)x(BN/WC), ring-2 LDS double buffer,
// counted vmcnt (wait only the tile staged one step ago), 2 k-half phases per step.
// Chunk-XOR LDS swizzle both-sides (rule #21): LDS[row][c] = G[row][c ^ (row&7)],
// achieved by pre-swizzling the per-lane GLOBAL src chunk (gload_lds dest stays linear);
// reads XOR the chunk with (row&7) -> 2-way bank conflict (free, m136).
// MODE 0: f32 out, no bias.  MODE 1: bf16 out + column bias.
template <int BM, int BN, int WC, int MODE>
__global__ __launch_bounds__(512) void k_mfma_gemm(
    const u16* __restrict__ A, const u16* __restrict__ B,
    float* __restrict__ Cf, u16* __restrict__ Cb,
    const float* __restrict__ bias, int K, int N)
{
    constexpr int WR = 8 / WC;
    constexpr int WM = BM / WR;          // wave-tile rows
    constexpr int WN = BN / WC;          // wave-tile cols
    constexpr int MR = WM / 16;
    constexpr int NR = WN / 16;
    constexpr int QA = BM / 64;          // gload16 insts per thread for A tile
    constexpr int QB = BN / 64;
    constexpr int S = QA + QB;           // per-wave vmem ops per stage
    __shared__ u16 As[2][BM * 64];
    __shared__ u16 Bs[2][BN * 64];
    int tid = threadIdx.x, lane = tid & 63, wave = tid >> 6;
    int wr = wave / WC, wc = wave % WC;
    int i0 = blockIdx.y * BM, j0 = blockIdx.x * BN;
    int fr = lane & 15, fg = lane >> 4;
    f32x4 acc[MR][NR] = {};

    int srcOff = ((tid & 7) ^ ((tid >> 3) & 7)) * 8;   // pre-swizzled global chunk (u16 units)

    auto stage = [&](int buf, int t) {
        int kt = t * 64;
        #pragma unroll
        for (int q = 0; q < QA; ++q) {
            int row = (q * 512 + tid) >> 3;
            gload16(A + (size_t)(i0 + row) * K + kt + srcOff,
                    &As[buf][(q * 512 + wave * 64) * 8]);
        }
        #pragma unroll
        for (int q = 0; q < QB; ++q) {
            int row = (q * 512 + tid) >> 3;
            gload16(B + (size_t)(j0 + row) * K + kt + srcOff,
                    &Bs[buf][(q * 512 + wave * 64) * 8]);
        }
    };
    auto compute = [&](int buf) {
        #pragma unroll
        for (int h = 0; h < 2; ++h) {               // two K=32 halves of the BK=64 tile
            bf16x8 af[MR], bv[NR];
            #pragma unroll
            for (int mi = 0; mi < MR; ++mi) {
                int row = wr * WM + mi * 16 + fr;
                af[mi] = *(const bf16x8*)&As[buf][row * 64 + ((h * 4 + fg) ^ (fr & 7)) * 8];
            }
            #pragma unroll
            for (int ni = 0; ni < NR; ++ni) {
                int row = wc * WN + ni * 16 + fr;
                bv[ni] = *(const bf16x8*)&Bs[buf][row * 64 + ((h * 4 + fg) ^ (fr & 7)) * 8];
            }
            #pragma unroll
            for (int mi = 0; mi < MR; ++mi)
                #pragma unroll
                for (int ni = 0; ni < NR; ++ni)
                    acc[mi][ni] = __builtin_amdgcn_mfma_f32_16x16x32_bf16(
                        af[mi], bv[ni], acc[mi][ni], 0, 0, 0);
        }
    };

    int nk = K >> 6;
    stage(0, 0);
    int cur = 0;
    for (int t = 0; t < nk; ++t) {
        if (t + 1 < nk) {
            stage(cur ^ 1, t + 1);                 // prefetch next tile (ring-2 is race-free:
                                                   // buf cur^1 readers finished before prev barrier)
            if constexpr (S == 6)       asm volatile("s_waitcnt vmcnt(6)" ::: "memory");
            else if constexpr (S == 4)  asm volatile("s_waitcnt vmcnt(4)" ::: "memory");
            else                        asm volatile("s_waitcnt vmcnt(8)" ::: "memory");
        } else {
            asm volatile("s_waitcnt vmcnt(0)" ::: "memory");
        }
        __builtin_amdgcn_s_barrier();              // all waves' loads for buf cur visible
        __builtin_amdgcn_sched_barrier(0);         // pin: no LDS read hoisted above barrier
        compute(cur);
        __builtin_amdgcn_s_barrier();              // all waves done reading buf cur
        cur ^= 1;
    }

    // epilogue: C/D layout col = lane&15, row = (lane>>4)*4 + r  [m89]
    if (MODE == 1) {
        #pragma unroll
        for (int ni = 0; ni < NR; ++ni) {
            int col = j0 + wc * WN + ni * 16 + fr;
            float bvv = bias[col];
            #pragma unroll
            for (int mi = 0; mi < MR; ++mi)
                #pragma unroll
                for (int r = 0; r < 4; ++r) {
                    int row = i0 + wr * WM + mi * 16 + fg * 4 + r;
                    Cb[(size_t)row * N + col] = f2bf(acc[mi][ni][r] + bvv);
                }
        }
    } else {
        #pragma unroll
        for (int ni = 0; ni < NR; ++ni) {
            int col = j0 + wc * WN + ni * 16 + fr;
            #pragma unroll
            for (int mi = 0; mi < MR; ++mi)
                #pragma unroll
                for (int r = 0; r < 4; ++r) {
                    int row = i0 + wr * WM + mi * 16 + fg * 4 + r;
                    Cf[(size_t)row * N + col] = acc[mi][ni][r];
                }
        }
    }
}

// ---------------- K3: alpha_g = sigmoid(h @ W_g^T + b_g), stored transposed [b][g][m] ----------------
__global__ __launch_bounds__(256) void k_alpha_g(const u16* __restrict__ h,
                                                 const float* __restrict__ Wg,
                                                 const float* __restrict__ bg,
                                                 float* __restrict__ agT) {
    __shared__ float wgl[16384];  // Wg [8][2048] f32 = 64KB
    int tid = threadIdx.x;
    #pragma unroll
    for (int i = 0; i < 16; ++i) {
        int idx = tid * 4 + i * 1024;
        *(float4*)&wgl[idx] = *(const float4*)&Wg[idx];
    }
    __syncthreads();
    float bgl[8];
    #pragma unroll
    for (int g = 0; g < 8; ++g) bgl[g] = bg[g];
    int wv = tid >> 6, lane = tid & 63;
    int bm0 = blockIdx.x * 16;
    for (int r = 0; r < 4; ++r) {
        int bm = bm0 + wv * 4 + r;
        const u16* hr = h + (size_t)bm * 2048;
        float acc[8] = {};
        #pragma unroll
        for (int i = 0; i < 4; ++i) {
            int c0 = i * 512 + lane * 8;
            bf16x8 hv8 = *(const bf16x8*)(hr + c0);
            float hf[8];
            #pragma unroll
            for (int j = 0; j < 8; ++j) hf[j] = bf2f((u16)hv8[j]);
            #pragma unroll
            for (int g = 0; g < 8; ++g) {
                const float* wrp = &wgl[g * 2048 + c0];
                #pragma unroll
                for (int j = 0; j < 8; ++j) acc[g] += hf[j] * wrp[j];
            }
        }
        #pragma unroll
        for (int g = 0; g < 8; ++g) {
            #pragma unroll
            for (int off = 32; off; off >>= 1) acc[g] += __shfl_xor(acc[g], off);
        }
        if (lane < 8) {
            int b = bm >> 10, m = bm & 1023;
            agT[((size_t)b * 8 + lane) * 1024 + m] =
                1.f / (1.f + expf(-(acc[lane] + bgl[lane])));
        }
    }
}

// ---------------- K4: softmax over m (lt row slice), * alpha_g, in-place; wsum ----------------
// lt layout: [gk][b*1024 + m]
__global__ __launch_bounds__(256) void k_softmax(float* __restrict__ lt,
                                                 const float* __restrict__ agT,
                                                 float* __restrict__ wsum) {
    int gk = blockIdx.x, b = blockIdx.y;
    int tid = threadIdx.x;
    float* row = lt + (size_t)gk * 4096 + b * 1024;
    int g = gk >> 7;
    const float* ag = agT + ((size_t)b * 8 + g) * 1024;
    __shared__ float red[4], red2[4], red3[4];
    float4 v = *(const float4*)(row + tid * 4);
    float mx = fmaxf(fmaxf(v.x, v.y), fmaxf(v.z, v.w));
    #pragma unroll
    for (int m = 32; m; m >>= 1) mx = fmaxf(mx, __shfl_xor(mx, m));
    if ((tid & 63) == 0) red[tid >> 6] = mx;
    __syncthreads();
    mx = fmaxf(fmaxf(red[0], red[1]), fmaxf(red[2], red[3]));
    float e0 = expf(v.x - mx), e1 = expf(v.y - mx), e2 = expf(v.z - mx), e3 = expf(v.w - mx);
    float s = e0 + e1 + e2 + e3;
    #pragma unroll
    for (int m = 32; m; m >>= 1) s += __shfl_xor(s, m);
    if ((tid & 63) == 0) red2[tid >> 6] = s;
    __syncthreads();
    s = red2[0] + red2[1] + red2[2] + red2[3];
    float invs = 1.f / s;
    float4 a = *(const float4*)(ag + tid * 4);
    float w0 = e0 * invs * a.x, w1 = e1 * invs * a.y, w2 = e2 * invs * a.z, w3 = e3 * invs * a.w;
    float4 o; o.x = w0; o.y = w1; o.z = w2; o.w = w3;
    *(float4*)(row + tid * 4) = o;
    float t = w0 + w1 + w2 + w3;
    #pragma unroll
    for (int m = 32; m; m >>= 1) t += __shfl_xor(t, m);
    if ((tid & 63) == 0) red3[tid >> 6] = t;
    __syncthreads();
    if (tid == 0) wsum[((size_t)b * 8 + g) * 128 + (gk & 127)] = red3[0] + red3[1] + red3[2] + red3[3];
}

// ---------------- K4b: wf[b,g,m] = sum_k Wf[k]*w[b,gk,m];  u = Wf*wsum ----------------
// w layout: [gk][b*1024+m]. grid (8 m-segs, 32 bg), k split 2x128 threads
__global__ __launch_bounds__(256) void k_wf_u(const float* __restrict__ wT,
                                              const float* __restrict__ wsum,
                                              const float* __restrict__ Wf,
                                              float* __restrict__ wf, float* __restrict__ u) {
    int ms = blockIdx.x, bg = blockIdx.y;
    int b = bg >> 3, g = bg & 7;
    int tid = threadIdx.x;
    __shared__ float wfl[128];
    __shared__ float part[256];
    if (tid < 128) {
        wfl[tid] = Wf[tid];
        if (ms == 0) u[bg * 128 + tid] = Wf[tid] * wsum[bg * 128 + tid];
    }
    __syncthreads();
    int ml = tid & 127;
    int kh = tid >> 7;
    const float* base = wT + (size_t)(g * 128 + kh * 64) * 4096 + (size_t)b * 1024 + ms * 128;
    float acc = 0.f;
    #pragma unroll 4
    for (int k = 0; k < 64; ++k) acc += wfl[kh * 64 + k] * base[(size_t)k * 4096 + ml];
    part[tid] = acc;
    __syncthreads();
    if (tid < 128) wf[(size_t)bg * 1024 + ms * 128 + ml] = part[tid] + part[tid + 128];
}

// ---------------- K5: vf partials: mc<16 -> sum_{m chunk} wf[m]*h; mc==16 -> -centroid term ----------------
__global__ __launch_bounds__(256) void k_vf_partial(const u16* __restrict__ h,
                                                    const float* __restrict__ wf,
                                                    const float* __restrict__ u,
                                                    const float* __restrict__ cent,
                                                    float* __restrict__ vfp) {
    int mc = blockIdx.x;  // 0..16
    int g = blockIdx.y, b = blockIdx.z;
    int d = threadIdx.x;
    __shared__ float wl[64];
    __shared__ float ul[128];
    float acc = 0.f;
    if (mc < 16) {
        if (d < 64) wl[d] = wf[((size_t)b * 8 + g) * 1024 + mc * 64 + d];
        __syncthreads();
        const u16* hb = h + (size_t)b * 1024 * 2048 + (size_t)(mc * 64) * 2048 + g * 256;
        #pragma unroll 4
        for (int m = 0; m < 64; ++m) acc += wl[m] * bf2f(hb[(size_t)m * 2048 + d]);
    } else {
        if (d < 128) ul[d] = u[((size_t)b * 8 + g) * 128 + d];
        __syncthreads();
        for (int k = 0; k < 128; ++k) acc -= ul[k] * cent[k * 256 + d];
    }
    vfp[(((size_t)b * 8 + g) * 17 + mc) * 256 + d] = acc;
}

// ---------------- K6: finalize vf, center, trace, S(8x8), rank-8 Newton-Schulz ----------------
#define MM8(DST, P, Q) do { if (act) { float s_ = 0.f; \
    _Pragma("unroll") \
    for (int l_ = 0; l_ < 8; ++l_) s_ += P[ii][l_] * Q[l_][jj]; \
    DST[ii][jj] = s_; } __syncthreads(); } while (0)

__global__ __launch_bounds__(256) void k_finalize(const float* __restrict__ vfp,
                                                  const float* __restrict__ bf,
                                                  float* __restrict__ VcOut,
                                                  float* __restrict__ Wrow,
                                                  float* __restrict__ s0) {
    int b = blockIdx.x;
    int tid = threadIdx.x;  // 256
    __shared__ float Vl[256][9];
    __shared__ float red[256];
    __shared__ float Sm[8][8], W1[8][8], W2[8][8], YmL[8][8], ZmL[8][8], ZYL[8][8], FmL[8][8];
    int d = tid;
    float bfv = bf[0];
    float vfl[8];
    #pragma unroll
    for (int g = 0; g < 8; ++g) {
        float acc = 0.f;
        for (int mc = 0; mc < 17; ++mc)
            acc += vfp[(((size_t)b * 8 + g) * 17 + mc) * 256 + d];
        vfl[g] = acc + bfv;
    }
    float mean = 0.f;
    #pragma unroll
    for (int g = 0; g < 8; ++g) mean += vfl[g];
    mean *= 0.125f;
    float trp = 0.f;
    #pragma unroll
    for (int g = 0; g < 8; ++g) { float v = vfl[g] - mean; Vl[d][g] = v; trp += v * v; }
    red[tid] = trp;
    __syncthreads();
    for (int s = 128; s > 0; s >>= 1) { if (tid < s) red[tid] += red[tid + s]; __syncthreads(); }
    float tr = red[0] * 0.125f;  // trace(cov)
    bool act = tid < 64;
    int ii = (tid >> 3) & 7, jj = tid & 7;
    if (act) {
        float sv = 0.f;
        for (int dd = 0; dd < 256; ++dd) sv += Vl[dd][ii] * Vl[dd][jj];
        Sm[ii][jj] = sv / (8.f * tr);
    }
    __syncthreads();
    // representation: mat = a*I + U B U^T, S = U^T U; product (a,P)(c,Q)=(ac, aQ+cP+P S Q)
    if (act) {
        YmL[ii][jj] = (ii == jj ? 1.5f : 0.f) - 0.5f * Sm[ii][jj];
        ZmL[ii][jj] = (ii == jj ? -0.5f : 0.f);
    }
    __syncthreads();
    float ya = 0.f, za = 1.5f;
    MM8(W1, Sm, YmL);
    MM8(W2, ZmL, W1);
    float pa = za * ya;
    if (act) ZYL[ii][jj] = -0.5f * (za * YmL[ii][jj] + ya * ZmL[ii][jj] + W2[ii][jj]);
    __syncthreads();
    float zya = 1.5f - 0.5f * pa;
    MM8(W1, Sm, ZYL);
    MM8(W2, YmL, W1);
    if (act) YmL[ii][jj] = ya * ZYL[ii][jj] + zya * YmL[ii][jj] + W2[ii][jj];
    __syncthreads();
    ya = ya * zya;
    MM8(W1, Sm, ZmL);
    MM8(W2, ZYL, W1);
    if (act) ZmL[ii][jj] = zya * ZmL[ii][jj] + za * ZYL[ii][jj] + W2[ii][jj];
    __syncthreads();
    za = zya * za;
    MM8(W1, Sm, YmL);
    MM8(W2, ZmL, W1);
    float p2a = za * ya;
    if (act) ZYL[ii][jj] = za * YmL[ii][jj] + ya * ZmL[ii][jj] + W2[ii][jj];
    __syncthreads();
    MM8(W1, Sm, ZYL);
    MM8(W2, YmL, W1);
    if (act) FmL[ii][jj] = 0.5f * ((3.f - p2a) * YmL[ii][jj] - ya * ZYL[ii][jj] - W2[ii][jj]);
    __syncthreads();
    float fa = 0.5f * ya * (3.f - p2a);
    float sqtr = sqrtf(tr);
    float scaleF = 1.f / (8.f * sqtr);
    #pragma unroll
    for (int jo = 0; jo < 8; ++jo) {
        float sv = 0.f;
        #pragma unroll
        for (int i = 0; i < 8; ++i) sv += Vl[d][i] * FmL[i][jo];
        Wrow[((size_t)b * 256 + d) * 8 + jo] = sv * scaleF;
    }
    #pragma unroll
    for (int jo = 0; jo < 8; ++jo) VcOut[((size_t)b * 256 + d) * 8 + jo] = Vl[d][jo];
    if (tid == 0) s0[b] = fa * sqtr;
}

// ---------------- K7: triuvec output: R[d,e] = s0*delta + Wrow[d,:].Vc[e,:] ----------------
__global__ __launch_bounds__(256) void k_output(const float* __restrict__ Vc,
                                                const float* __restrict__ Wrow,
                                                const float* __restrict__ s0,
                                                float* __restrict__ out) {
    int dd = blockIdx.x, b = blockIdx.y;
    int e = threadIdx.x;
    __shared__ float Vl[256][9];
    __shared__ float wr[8];
    float4 v0 = *(const float4*)(Vc + ((size_t)b * 256 + e) * 8);
    float4 v1 = *(const float4*)(Vc + ((size_t)b * 256 + e) * 8 + 4);
    Vl[e][0] = v0.x; Vl[e][1] = v0.y; Vl[e][2] = v0.z; Vl[e][3] = v0.w;
    Vl[e][4] = v1.x; Vl[e][5] = v1.y; Vl[e][6] = v1.z; Vl[e][7] = v1.w;
    if (e < 8) wr[e] = Wrow[((size_t)b * 256 + dd) * 8 + e];
    __syncthreads();
    if (e >= dd) {
        float v = (e == dd) ? s0[b] : 0.f;
        #pragma unroll
        for (int j = 0; j < 8; ++j) v += wr[j] * Vl[e][j];
        size_t idx = (size_t)b * 32896 + (size_t)dd * 256 - ((size_t)dd * (dd - 1)) / 2 + (e - dd);
        out[idx] = v;
    }
}

extern "C" void kernel_launch(void* const* d_in, const int* in_sizes, int n_in,
                              void* d_out, int out_size, void* d_ws, size_t ws_size,
                              hipStream_t stream) {
    const float* x    = (const float*)d_in[0];
    const float* cent = (const float*)d_in[1];
    const float* Winp = (const float*)d_in[2];
    const float* binp = (const float*)d_in[3];
    const float* Wg   = (const float*)d_in[4];
    const float* bg   = (const float*)d_in[5];
    const float* Wgk  = (const float*)d_in[6];
    const float* Wf   = (const float*)d_in[8];
    const float* bf   = (const float*)d_in[9];
    float* out = (float*)d_out;
    char* wsb = (char*)d_ws;

    // byte-offset workspace layout
    float* lt    = (float*)(wsb);                        // [1024][4096] f32, 16 MB
    u16*   xtnb  = (u16*)(wsb);                          // alias (dead before lt written), 8 MB
    u16*   hb    = (u16*)(wsb + (16ull << 20));          // [4096][2048] bf16, 16 MB
    u16*   winpb = (u16*)(wsb + (32ull << 20));          // [2048][1024] bf16, 4 MB
    u16*   wgkb  = (u16*)(wsb + (36ull << 20));          // [1024][2048] bf16, 4 MB (adjacent)
    float* agT   = (float*)(wsb + (40ull << 20));
    float* wsum  = agT + 32768;
    float* wf    = wsum + 4096;
    float* u     = wf + 32768;
    float* vfp   = u + 4096;                             // [4][8][17][256]
    float* Vc    = vfp + 139264;
    float* Wr    = Vc + 8192;
    float* s0    = Wr + 8192;

    k_transpose_norm<<<dim3(32, 16), 256, 0, stream>>>(x, xtnb);
    k_f2bf2<<<4096, 256, 0, stream>>>(Winp, Wgk, winpb, 2097152, 4194304);
    // GEMM1: h[bm,j] = xtn @ W_inp^T + b_inp -> bf16  (M=4096, N=2048, K=1024)
    // BM=256, BN=128, 8 waves 4x2 (wave 64x64), grid 16x16 = 256 blocks = 1/CU
    k_mfma_gemm<256, 128, 2, 1><<<dim3(16, 16), 512, 0, stream>>>(
        xtnb, winpb, nullptr, hb, binp, 1024, 2048);
    k_alpha_g<<<256, 256, 0, stream>>>(hb, Wg, bg, agT);
    // GEMM2 (merged batch): lt[gk][b*1024+m] = W_gk @ h^T  (M=1024, N=4096, K=2048)
    // BM=128, BN=128, 8 waves 2x4 (wave 64x32), grid 32x8 = 256 blocks = 1/CU
    // (bias omitted: softmax over m is shift-invariant)
    k_mfma_gemm<128, 128, 4, 0><<<dim3(32, 8), 512, 0, stream>>>(
        wgkb, hb, lt, nullptr, nullptr, 2048, 4096);
    k_softmax<<<dim3(1024, 4), 256, 0, stream>>>(lt, agT, wsum);
    k_wf_u<<<dim3(8, 32), 256, 0, stream>>>(lt, wsum, Wf, wf, u);
    k_vf_partial<<<dim3(17, 8, 4), 256, 0, stream>>>(hb, wf, u, cent, vfp);
    k_finalize<<<4, 256, 0, stream>>>(vfp, bf, Vc, Wr, s0);
    k_output<<<dim3(256, 4), 256, 0, stream>>>(Vc, Wr, s0, out);
}